// Round 1
// baseline (229.221 us; speedup 1.0000x reference)
//
#include <hip/hip_runtime.h>
#include <math.h>

#define H 256
#define V 10000
#define COLSN 64
#define ROWSN 200000
#define T_STEPS 4
#define QLEN 40
#define NNUM 5
#define NOPS 9

// workspace float offsets
#define WS_XWB   0          // 40*256 : X@Wx + b
#define WS_Q     10240      // 256
#define WS_HHA   10496      // 256 (h_hist ping)
#define WS_HHB   10752      // 256 (h_hist pong)
#define WS_POP   11008      // 256 : W_op[:, :256] @ q
#define WS_PCOL  11264      // 256
#define WS_UOP   11520      // 256
#define WS_UCOL  11776      // 256
#define WS_AOP   12032      // 4*16 (9 used per t)
#define WS_ACOL  12096      // 4*64
#define WS_CVEC  12352      // 512
#define WS_PIV   12864      // [0]=g_pivot [1]=l_pivot
#define WS_ACC   12872      // dot[4], cnt[4]

// ---- X@Wx + b, and zero the accumulators ----
__global__ void k_xw(const int* __restrict__ iq, const float* __restrict__ E,
                     const float* __restrict__ Wx, const float* __restrict__ b,
                     float* __restrict__ ws) {
    int t = blockIdx.x;
    int i = threadIdx.x;
    if (t == 0 && i < 8) ws[WS_ACC + i] = 0.f;
    int word = iq[t];
    const float* erow = E + (long)word * H;
    float acc = b[i];
    #pragma unroll 8
    for (int j = 0; j < H; ++j) acc += erow[j] * Wx[j * H + i];
    ws[WS_XWB + t * H + i] = acc;
}

// ---- question RNN (sequential, Wh register-resident), pivots ----
__global__ void k_rnn(const float* __restrict__ Wh, const int* __restrict__ lwi,
                      const float* __restrict__ U, const float* __restrict__ qn,
                      float* __restrict__ ws) {
    __shared__ float h[H];
    __shared__ float part[H];
    __shared__ float Z[NNUM][H];
    __shared__ float lg[10];
    int tid = threadIdx.x;       // 512 threads
    int i = tid & (H - 1);
    int p = tid >> 8;            // 0 or 1 : which half of j-range
    float w[128];
    #pragma unroll
    for (int jj = 0; jj < 128; ++jj) w[jj] = Wh[(p * 128 + jj) * H + i];
    if (tid < H) h[tid] = 0.f;
    __syncthreads();
    int lw0 = lwi[0], lw1 = lwi[1], lw2 = lwi[2], lw3 = lwi[3], lw4 = lwi[4];
    for (int t = 0; t < QLEN; ++t) {
        float acc = 0.f;
        const float4* h4 = (const float4*)&h[p * 128];
        #pragma unroll
        for (int q4 = 0; q4 < 32; ++q4) {
            float4 hv = h4[q4];
            acc += hv.x * w[q4 * 4 + 0];
            acc += hv.y * w[q4 * 4 + 1];
            acc += hv.z * w[q4 * 4 + 2];
            acc += hv.w * w[q4 * 4 + 3];
        }
        if (p == 1) part[i] = acc;
        __syncthreads();
        if (p == 0) {
            float v = ws[WS_XWB + t * H + i] + acc + part[i];
            float hn = tanhf(v);
            h[i] = hn;
            if (t == lw0) Z[0][i] = hn;
            if (t == lw1) Z[1][i] = hn;
            if (t == lw2) Z[2][i] = hn;
            if (t == lw3) Z[3][i] = hn;
            if (t == lw4) Z[4][i] = hn;
        }
        __syncthreads();
    }
    if (tid < H) { ws[WS_Q + tid] = h[tid]; ws[WS_HHA + tid] = 0.f; }
    if (tid < 10) {
        int n = tid % 5, u = tid / 5;
        float s = 0.f;
        for (int j = 0; j < H; ++j) s += Z[n][j] * U[u * H + j];
        lg[tid] = s;
    }
    __syncthreads();
    if (tid < 2) {
        // tid==0: u=0 (lesser pivot), tid==1: u=1 (greater pivot)
        float m = -1e30f;
        for (int n = 0; n < 5; ++n) m = fmaxf(m, lg[tid * 5 + n]);
        float e[5], s = 0.f;
        for (int n = 0; n < 5; ++n) { e[n] = expf(lg[tid * 5 + n] - m); s += e[n]; }
        float piv = 0.f;
        for (int n = 0; n < 5; ++n) piv += (e[n] / s) * qn[n];
        ws[WS_PIV + (tid == 0 ? 1 : 0)] = piv;   // PIV[0]=g, PIV[1]=l
    }
}

// ---- P_op = W_op[:, :256]@q, P_col = W_col[:, :256]@q ----
__global__ void k_pq(const float* __restrict__ W_op, const float* __restrict__ W_col,
                     float* __restrict__ ws) {
    __shared__ float q[H];
    int tid = threadIdx.x;
    q[tid] = ws[WS_Q + tid];
    __syncthreads();
    const float* W = (blockIdx.x == 0) ? W_op : W_col;
    int dst = (blockIdx.x == 0) ? WS_POP : WS_PCOL;
    const float* row = W + tid * (2 * H);
    float acc = 0.f;
    #pragma unroll 8
    for (int j = 0; j < H; ++j) acc += row[j] * q[j];
    ws[dst + tid] = acc;
}

// ---- u_op/u_col = tanh(P + W[:,256:] @ h_hist) ----
__global__ void k_u(const float* __restrict__ W_op, const float* __restrict__ W_col,
                    const float* __restrict__ hsrc, float* __restrict__ ws) {
    __shared__ float hh[H];
    int tid = threadIdx.x;
    hh[tid] = hsrc[tid];
    __syncthreads();
    int g = blockIdx.x * 32 + (tid >> 3);
    int pp = tid & 7;
    const float* W; int r, pofs, dofs;
    if (g < H) { W = W_op;  r = g;     pofs = WS_POP;  dofs = WS_UOP; }
    else       { W = W_col; r = g - H; pofs = WS_PCOL; dofs = WS_UCOL; }
    const float* row = W + r * (2 * H) + H + pp * 32;
    const float* hp = &hh[pp * 32];
    float s = 0.f;
    #pragma unroll
    for (int jj = 0; jj < 32; ++jj) s += row[jj] * hp[jj];
    s += __shfl_xor(s, 1);
    s += __shfl_xor(s, 2);
    s += __shfl_xor(s, 4);
    if (pp == 0) ws[dofs + r] = tanhf(ws[pofs + r] + s);
}

// ---- logits, softmaxes, c = [a_op@op_emb, a_col@col_emb] ----
__global__ void k_soft(int t, const float* __restrict__ op_emb,
                       const float* __restrict__ col_emb, float* __restrict__ ws) {
    __shared__ float uo[H], uc[H];
    __shared__ float lop[NOPS], lcol[COLSN];
    __shared__ float aop[NOPS], acol[COLSN];
    int tid = threadIdx.x;
    uo[tid] = ws[WS_UOP + tid];
    uc[tid] = ws[WS_UCOL + tid];
    __syncthreads();
    if (tid < COLSN) {
        const float* row = col_emb + tid * H;
        float s = 0.f;
        for (int j = 0; j < H; ++j) s += row[j] * uc[j];
        lcol[tid] = s;
    } else if (tid >= 64 && tid < 64 + NOPS) {
        int k = tid - 64;
        const float* row = op_emb + k * H;
        float s = 0.f;
        for (int j = 0; j < H; ++j) s += row[j] * uo[j];
        lop[k] = s;
    }
    __syncthreads();
    if (tid == 0) {
        float m = -1e30f; for (int k = 0; k < NOPS; ++k) m = fmaxf(m, lop[k]);
        float e[NOPS], s = 0.f;
        for (int k = 0; k < NOPS; ++k) { e[k] = expf(lop[k] - m); s += e[k]; }
        for (int k = 0; k < NOPS; ++k) { aop[k] = e[k] / s; ws[WS_AOP + t * 16 + k] = aop[k]; }
    }
    if (tid == 64) {
        float m = -1e30f; for (int k = 0; k < COLSN; ++k) m = fmaxf(m, lcol[k]);
        float s = 0.f;
        for (int k = 0; k < COLSN; ++k) { acol[k] = expf(lcol[k] - m); s += acol[k]; }
        float inv = 1.f / s;
        for (int k = 0; k < COLSN; ++k) { acol[k] *= inv; ws[WS_ACOL + t * COLSN + k] = acol[k]; }
    }
    __syncthreads();
    float cop = 0.f;
    #pragma unroll
    for (int k = 0; k < NOPS; ++k) cop += aop[k] * op_emb[k * H + tid];
    ws[WS_CVEC + tid] = cop;
    float ccol = 0.f;
    #pragma unroll
    for (int k = 0; k < COLSN; ++k) ccol += acol[k] * col_emb[k * H + tid];
    ws[WS_CVEC + H + tid] = ccol;
}

// ---- h_hist update: h_new = tanh(W_hc@c + W_hh@h_hist)  (ping-pong) ----
__global__ void k_h(const float* __restrict__ W_hc, const float* __restrict__ W_hh,
                    const float* __restrict__ hsrc, float* __restrict__ hdst,
                    const float* __restrict__ ws) {
    __shared__ float c[2 * H];
    __shared__ float hh[H];
    int tid = threadIdx.x;
    c[tid] = ws[WS_CVEC + tid];
    c[H + tid] = ws[WS_CVEC + H + tid];
    hh[tid] = hsrc[tid];
    __syncthreads();
    int r = blockIdx.x * 32 + (tid >> 3);
    int pp = tid & 7;
    float s = 0.f;
    const float* rowc = W_hc + r * (2 * H) + pp * 64;
    const float* cc = &c[pp * 64];
    #pragma unroll
    for (int jj = 0; jj < 64; ++jj) s += rowc[jj] * cc[jj];
    const float* rowh = W_hh + r * H + pp * 32;
    const float* hp = &hh[pp * 32];
    #pragma unroll
    for (int jj = 0; jj < 32; ++jj) s += rowh[jj] * hp[jj];
    s += __shfl_xor(s, 1);
    s += __shfl_xor(s, 2);
    s += __shfl_xor(s, 4);
    if (pp == 0) hdst[r] = tanhf(s);
}

// ---- single pass over the table: row_select chain, reductions, lookup write ----
__global__ __launch_bounds__(256) void k_table(const float* __restrict__ table,
                                               float* __restrict__ ws,
                                               float* __restrict__ out) {
    __shared__ float acol[4 * COLSN];
    __shared__ float aop[4 * 16];
    __shared__ float rs3[256];
    __shared__ float wred[4][8];
    int tid = threadIdx.x;
    acol[tid] = ws[WS_ACOL + tid];          // 256 = 4*64
    if (tid < 64) aop[tid] = ws[WS_AOP + tid];
    __syncthreads();
    float gp = ws[WS_PIV + 0];
    float lp = ws[WS_PIV + 1];
    long r = (long)blockIdx.x * 256 + tid;
    bool valid = r < ROWSN;
    float cv[4] = {0,0,0,0}, gs[4] = {0,0,0,0}, ls[4] = {0,0,0,0};
    if (valid) {
        const float4* row4 = (const float4*)(table + r * COLSN);
        #pragma unroll
        for (int c4 = 0; c4 < 16; ++c4) {
            float4 v = row4[c4];
            float xs[4] = {v.x, v.y, v.z, v.w};
            #pragma unroll
            for (int e = 0; e < 4; ++e) {
                int c = c4 * 4 + e;
                float x = xs[e];
                float gt = (x > gp) ? 1.f : 0.f;
                float lt = (x < lp) ? 1.f : 0.f;
                #pragma unroll
                for (int t = 0; t < 4; ++t) {
                    float a = acol[t * COLSN + c];
                    cv[t] += x * a;
                    gs[t] += gt * a;
                    ls[t] += lt * a;
                }
            }
        }
    }
    float prev1 = 1.f, prev2 = 1.f;
    float dotp[4], cntp[4];
    #pragma unroll
    for (int t = 0; t < 4; ++t) {
        dotp[t] = valid ? prev1 * cv[t] : 0.f;
        cntp[t] = valid ? prev1 : 0.f;
        float cg = aop[t*16+3], cl = aop[t*16+4], cmn = aop[t*16+5];
        float cmx = aop[t*16+6], co = aop[t*16+8];
        float cid = aop[t*16+0] + aop[t*16+1] + aop[t*16+2] + aop[t*16+7];
        float rsn = cg * gs[t] + cl * ls[t] + cmn * fminf(prev1, prev2)
                  + cmx * fmaxf(prev1, prev2) + co + cid * prev1;
        prev2 = prev1; prev1 = rsn;
    }
    rs3[tid] = valid ? prev1 * aop[3*16+7] : 0.f;
    __syncthreads();
    // coalesced lookup write (offset by 1 for the scalar output slot)
    long base = (long)blockIdx.x * 256 * COLSN;
    long lim = (long)ROWSN * COLSN;
    for (int idx = tid; idx < 256 * COLSN; idx += 256) {
        long o = base + idx;
        if (o < lim) out[1 + o] = rs3[idx >> 6] * acol[3 * COLSN + (idx & 63)];
    }
    // block-reduce dot[t], cnt[t] then one atomicAdd per block
    #pragma unroll
    for (int t = 0; t < 4; ++t) {
        float d = dotp[t], cn = cntp[t];
        for (int off = 1; off < 64; off <<= 1) { d += __shfl_xor(d, off); cn += __shfl_xor(cn, off); }
        if ((tid & 63) == 0) { int wid = tid >> 6; wred[wid][t] = d; wred[wid][4 + t] = cn; }
    }
    __syncthreads();
    if (tid < 8) {
        float s = wred[0][tid] + wred[1][tid] + wred[2][tid] + wred[3][tid];
        atomicAdd(&ws[WS_ACC + tid], s);
    }
}

// ---- scalar chain ----
__global__ void k_scalar(const float* __restrict__ ws, float* __restrict__ out) {
    float d0 = ws[WS_ACC+0], d1 = ws[WS_ACC+1], d2 = ws[WS_ACC+2], d3 = ws[WS_ACC+3];
    float c0 = ws[WS_ACC+4], c1 = ws[WS_ACC+5], c2 = ws[WS_ACC+6], c3 = ws[WS_ACC+7];
    const float* a0 = &ws[WS_AOP + 0];
    const float* a1 = &ws[WS_AOP + 16];
    const float* a2 = &ws[WS_AOP + 32];
    const float* a3 = &ws[WS_AOP + 48];
    float s0 = a0[0]*d0 + a0[1]*c0;                      // s1=s3=0 at t=0
    float s1 = a1[0]*d1 + a1[1]*c1 + a1[2]*(0.f - s0);
    float s2 = a2[0]*d2 + a2[1]*c2 + a2[2]*(0.f - s1);
    float s3 = a3[0]*d3 + a3[1]*c3 + a3[2]*(s0 - s2);
    out[0] = s3;
}

extern "C" void kernel_launch(void* const* d_in, const int* in_sizes, int n_in,
                              void* d_out, int out_size, void* d_ws, size_t ws_size,
                              hipStream_t stream) {
    const int*   iq      = (const int*)  d_in[0];
    const float* qn      = (const float*)d_in[1];
    const int*   lwi     = (const int*)  d_in[2];
    const float* table   = (const float*)d_in[3];
    const float* E       = (const float*)d_in[4];
    const float* Wx      = (const float*)d_in[5];
    const float* Wh      = (const float*)d_in[6];
    const float* b       = (const float*)d_in[7];
    const float* W_op    = (const float*)d_in[8];
    const float* op_emb  = (const float*)d_in[9];
    const float* W_col   = (const float*)d_in[10];
    const float* col_emb = (const float*)d_in[11];
    const float* U       = (const float*)d_in[12];
    const float* W_hc    = (const float*)d_in[13];
    const float* W_hh    = (const float*)d_in[14];
    float* out = (float*)d_out;
    float* ws  = (float*)d_ws;

    hipLaunchKernelGGL(k_xw,  dim3(QLEN), dim3(H),   0, stream, iq, E, Wx, b, ws);
    hipLaunchKernelGGL(k_rnn, dim3(1),    dim3(512), 0, stream, Wh, lwi, U, qn, ws);
    hipLaunchKernelGGL(k_pq,  dim3(2),    dim3(H),   0, stream, W_op, W_col, ws);
    for (int t = 0; t < T_STEPS; ++t) {
        float* hsrc = ws + ((t & 1) ? WS_HHB : WS_HHA);
        float* hdst = ws + ((t & 1) ? WS_HHA : WS_HHB);
        hipLaunchKernelGGL(k_u,    dim3(16), dim3(256), 0, stream, W_op, W_col, hsrc, ws);
        hipLaunchKernelGGL(k_soft, dim3(1),  dim3(256), 0, stream, t, op_emb, col_emb, ws);
        hipLaunchKernelGGL(k_h,    dim3(8),  dim3(256), 0, stream, W_hc, W_hh, hsrc, hdst, ws);
    }
    hipLaunchKernelGGL(k_table,  dim3((ROWSN + 255) / 256), dim3(256), 0, stream, table, ws, out);
    hipLaunchKernelGGL(k_scalar, dim3(1), dim3(1), 0, stream, ws, out);
}

// Round 2
// 181.410 us; speedup vs baseline: 1.2636x; 1.2636x over previous
//
#include <hip/hip_runtime.h>
#include <math.h>

#define H 256
#define V 10000
#define COLSN 64
#define ROWSN 200000
#define T_STEPS 4
#define QLEN 40
#define NNUM 5
#define NOPS 9

// workspace float offsets
#define WS_XWB   0          // 40*256 : X@Wx + b
#define WS_Q     10240      // 256
#define WS_HHA   10496      // 256 (h_hist ping)
#define WS_HHB   10752      // 256 (h_hist pong)
#define WS_POP   11008      // 256 : W_op[:, :256] @ q
#define WS_PCOL  11264      // 256
#define WS_UOP   11520      // 256
#define WS_UCOL  11776      // 256
#define WS_AOP   12032      // 4*16 (9 used per t)
#define WS_ACOL  12096      // 4*64
#define WS_CVEC  12352      // 512
#define WS_PIV   12864      // [0]=g_pivot [1]=l_pivot
#define WS_ACC   12872      // dot[4], cnt[4]

// DPP-based partial-sum add (VALU pipe, avoids ds_swizzle on the LDS pipe)
template<int CTRL>
__device__ __forceinline__ float dpp_add(float x) {
    int xi = __float_as_int(x);
    int yi = __builtin_amdgcn_update_dpp(0, xi, CTRL, 0xF, 0xF, true);
    return x + __int_as_float(yi);
}
#define DPP_XOR1 0xB1   // quad_perm [1,0,3,2]
#define DPP_XOR2 0x4E   // quad_perm [2,3,0,1]
#define DPP_HMIR 0x141  // row_half_mirror (lane ^ 7)

__device__ __forceinline__ float fast_tanh(float x) {
    float cx = fminf(15.f, fmaxf(-15.f, x));
    float e = __expf(2.f * cx);
    return __fdividef(e - 1.f, e + 1.f);
}

// ---- X@Wx + b, and zero the accumulators ----
__global__ void k_xw(const int* __restrict__ iq, const float* __restrict__ E,
                     const float* __restrict__ Wx, const float* __restrict__ b,
                     float* __restrict__ ws) {
    int t = blockIdx.x;
    int i = threadIdx.x;
    if (t == 0 && i < 8) ws[WS_ACC + i] = 0.f;
    int word = iq[t];
    const float* erow = E + (long)word * H;
    float acc = b[i];
    #pragma unroll 8
    for (int j = 0; j < H; ++j) acc += erow[j] * Wx[j * H + i];
    ws[WS_XWB + t * H + i] = acc;
}

// ---- question RNN: 512 threads, R=4 outputs x P=8 j-slices per thread ----
// Wh register-resident (128 VGPR/thread), xwb in LDS, DPP reduction,
// double-buffered h (one barrier per step), fast tanh.
__global__ __launch_bounds__(512) void k_rnn(const float* __restrict__ Wh,
                      const int* __restrict__ lwi,
                      const float* __restrict__ U, const float* __restrict__ qn,
                      float* __restrict__ ws) {
    __shared__ float hbuf[2][H];
    __shared__ float xwb[QLEN][H];
    __shared__ float Z[NNUM][H];
    __shared__ float lg[10];
    int tid = threadIdx.x;       // 512
    int g = tid >> 3;            // output group 0..63  (outputs i = g*4+r)
    int p = tid & 7;             // j-slice 0..7        (j = p*32 .. p*32+31)

    // Wh fragment: w4[jj] = Wh[(p*32+jj)][g*4 .. g*4+3]  (coalesced float4)
    float4 w4[32];
    #pragma unroll
    for (int jj = 0; jj < 32; ++jj)
        w4[jj] = *(const float4*)&Wh[(p * 32 + jj) * H + g * 4];

    // preload X@Wx+b into LDS (40 KB)
    {
        const float4* src = (const float4*)&ws[WS_XWB];
        float4* dst = (float4*)&xwb[0][0];
        for (int idx = tid; idx < QLEN * H / 4; idx += 512) dst[idx] = src[idx];
    }
    if (tid < H) hbuf[0][tid] = 0.f;
    __syncthreads();

    int lw0 = lwi[0], lw1 = lwi[1], lw2 = lwi[2], lw3 = lwi[3], lw4 = lwi[4];
    int cur = 0;
    for (int t = 0; t < QLEN; ++t) {
        const float4* hv = (const float4*)&hbuf[cur][p * 32];
        float a0 = 0.f, a1 = 0.f, a2 = 0.f, a3 = 0.f;
        #pragma unroll
        for (int q4 = 0; q4 < 8; ++q4) {
            float4 h4 = hv[q4];
            float hs[4] = {h4.x, h4.y, h4.z, h4.w};
            #pragma unroll
            for (int e = 0; e < 4; ++e) {
                float hj = hs[e];
                float4 w = w4[q4 * 4 + e];
                a0 += hj * w.x;
                a1 += hj * w.y;
                a2 += hj * w.z;
                a3 += hj * w.w;
            }
        }
        // reduce over the 8 p-lanes (all within one 16-lane DPP row)
        a0 = dpp_add<DPP_XOR1>(a0); a0 = dpp_add<DPP_XOR2>(a0); a0 = dpp_add<DPP_HMIR>(a0);
        a1 = dpp_add<DPP_XOR1>(a1); a1 = dpp_add<DPP_XOR2>(a1); a1 = dpp_add<DPP_HMIR>(a1);
        a2 = dpp_add<DPP_XOR1>(a2); a2 = dpp_add<DPP_XOR2>(a2); a2 = dpp_add<DPP_HMIR>(a2);
        a3 = dpp_add<DPP_XOR1>(a3); a3 = dpp_add<DPP_XOR2>(a3); a3 = dpp_add<DPP_HMIR>(a3);
        if (p < 4) {
            float s = (p == 0) ? a0 : (p == 1) ? a1 : (p == 2) ? a2 : a3;
            int i = g * 4 + p;
            float hn = fast_tanh(xwb[t][i] + s);
            hbuf[cur ^ 1][i] = hn;
            if (t == lw0) Z[0][i] = hn;
            if (t == lw1) Z[1][i] = hn;
            if (t == lw2) Z[2][i] = hn;
            if (t == lw3) Z[3][i] = hn;
            if (t == lw4) Z[4][i] = hn;
        }
        __syncthreads();
        cur ^= 1;
    }
    if (tid < H) { ws[WS_Q + tid] = hbuf[cur][tid]; ws[WS_HHA + tid] = 0.f; }

    // pivot logits: 10 dots of 256, one 32-lane group each
    int grp = tid >> 5;          // 0..15
    int lane = tid & 31;
    if (grp < 10) {
        int u = grp / 5, n = grp % 5;
        float s = 0.f;
        #pragma unroll
        for (int k = 0; k < 8; ++k) {
            int j = lane + k * 32;
            s += Z[n][j] * U[u * H + j];
        }
        s += __shfl_xor(s, 1);
        s += __shfl_xor(s, 2);
        s += __shfl_xor(s, 4);
        s += __shfl_xor(s, 8);
        s += __shfl_xor(s, 16);
        if (lane == 0) lg[grp] = s;
    }
    __syncthreads();
    if (tid < 2) {
        // tid==0: u=0 (lesser pivot), tid==1: u=1 (greater pivot)
        float m = -1e30f;
        for (int n = 0; n < 5; ++n) m = fmaxf(m, lg[tid * 5 + n]);
        float e[5], s = 0.f;
        for (int n = 0; n < 5; ++n) { e[n] = expf(lg[tid * 5 + n] - m); s += e[n]; }
        float piv = 0.f;
        for (int n = 0; n < 5; ++n) piv += (e[n] / s) * qn[n];
        ws[WS_PIV + (tid == 0 ? 1 : 0)] = piv;   // PIV[0]=g, PIV[1]=l
    }
}

// ---- P_op = W_op[:, :256]@q, P_col = W_col[:, :256]@q ----
__global__ void k_pq(const float* __restrict__ W_op, const float* __restrict__ W_col,
                     float* __restrict__ ws) {
    __shared__ float q[H];
    int tid = threadIdx.x;
    q[tid] = ws[WS_Q + tid];
    __syncthreads();
    const float* W = (blockIdx.x == 0) ? W_op : W_col;
    int dst = (blockIdx.x == 0) ? WS_POP : WS_PCOL;
    const float* row = W + tid * (2 * H);
    float acc = 0.f;
    #pragma unroll 8
    for (int j = 0; j < H; ++j) acc += row[j] * q[j];
    ws[dst + tid] = acc;
}

// ---- u_op/u_col = tanh(P + W[:,256:] @ h_hist) ----
__global__ void k_u(const float* __restrict__ W_op, const float* __restrict__ W_col,
                    const float* __restrict__ hsrc, float* __restrict__ ws) {
    __shared__ float hh[H];
    int tid = threadIdx.x;
    hh[tid] = hsrc[tid];
    __syncthreads();
    int g = blockIdx.x * 32 + (tid >> 3);
    int pp = tid & 7;
    const float* W; int r, pofs, dofs;
    if (g < H) { W = W_op;  r = g;     pofs = WS_POP;  dofs = WS_UOP; }
    else       { W = W_col; r = g - H; pofs = WS_PCOL; dofs = WS_UCOL; }
    const float* row = W + r * (2 * H) + H + pp * 32;
    const float* hp = &hh[pp * 32];
    float s = 0.f;
    #pragma unroll
    for (int jj = 0; jj < 32; ++jj) s += row[jj] * hp[jj];
    s += __shfl_xor(s, 1);
    s += __shfl_xor(s, 2);
    s += __shfl_xor(s, 4);
    if (pp == 0) ws[dofs + r] = tanhf(ws[pofs + r] + s);
}

// ---- logits, softmaxes, c = [a_op@op_emb, a_col@col_emb] ----
__global__ void k_soft(int t, const float* __restrict__ op_emb,
                       const float* __restrict__ col_emb, float* __restrict__ ws) {
    __shared__ float uo[H], uc[H];
    __shared__ float lop[NOPS], lcol[COLSN];
    __shared__ float aop[NOPS], acol[COLSN];
    int tid = threadIdx.x;
    uo[tid] = ws[WS_UOP + tid];
    uc[tid] = ws[WS_UCOL + tid];
    __syncthreads();
    if (tid < COLSN) {
        const float* row = col_emb + tid * H;
        float s = 0.f;
        for (int j = 0; j < H; ++j) s += row[j] * uc[j];
        lcol[tid] = s;
    } else if (tid >= 64 && tid < 64 + NOPS) {
        int k = tid - 64;
        const float* row = op_emb + k * H;
        float s = 0.f;
        for (int j = 0; j < H; ++j) s += row[j] * uo[j];
        lop[k] = s;
    }
    __syncthreads();
    if (tid == 0) {
        float m = -1e30f; for (int k = 0; k < NOPS; ++k) m = fmaxf(m, lop[k]);
        float e[NOPS], s = 0.f;
        for (int k = 0; k < NOPS; ++k) { e[k] = expf(lop[k] - m); s += e[k]; }
        for (int k = 0; k < NOPS; ++k) { aop[k] = e[k] / s; ws[WS_AOP + t * 16 + k] = aop[k]; }
    }
    if (tid == 64) {
        float m = -1e30f; for (int k = 0; k < COLSN; ++k) m = fmaxf(m, lcol[k]);
        float s = 0.f;
        for (int k = 0; k < COLSN; ++k) { acol[k] = expf(lcol[k] - m); s += acol[k]; }
        float inv = 1.f / s;
        for (int k = 0; k < COLSN; ++k) { acol[k] *= inv; ws[WS_ACOL + t * COLSN + k] = acol[k]; }
    }
    __syncthreads();
    float cop = 0.f;
    #pragma unroll
    for (int k = 0; k < NOPS; ++k) cop += aop[k] * op_emb[k * H + tid];
    ws[WS_CVEC + tid] = cop;
    float ccol = 0.f;
    #pragma unroll
    for (int k = 0; k < COLSN; ++k) ccol += acol[k] * col_emb[k * H + tid];
    ws[WS_CVEC + H + tid] = ccol;
}

// ---- h_hist update: h_new = tanh(W_hc@c + W_hh@h_hist)  (ping-pong) ----
__global__ void k_h(const float* __restrict__ W_hc, const float* __restrict__ W_hh,
                    const float* __restrict__ hsrc, float* __restrict__ hdst,
                    const float* __restrict__ ws) {
    __shared__ float c[2 * H];
    __shared__ float hh[H];
    int tid = threadIdx.x;
    c[tid] = ws[WS_CVEC + tid];
    c[H + tid] = ws[WS_CVEC + H + tid];
    hh[tid] = hsrc[tid];
    __syncthreads();
    int r = blockIdx.x * 32 + (tid >> 3);
    int pp = tid & 7;
    float s = 0.f;
    const float* rowc = W_hc + r * (2 * H) + pp * 64;
    const float* cc = &c[pp * 64];
    #pragma unroll
    for (int jj = 0; jj < 64; ++jj) s += rowc[jj] * cc[jj];
    const float* rowh = W_hh + r * H + pp * 32;
    const float* hp = &hh[pp * 32];
    #pragma unroll
    for (int jj = 0; jj < 32; ++jj) s += rowh[jj] * hp[jj];
    s += __shfl_xor(s, 1);
    s += __shfl_xor(s, 2);
    s += __shfl_xor(s, 4);
    if (pp == 0) hdst[r] = tanhf(s);
}

// ---- single pass over the table: row_select chain, reductions, lookup write ----
__global__ __launch_bounds__(256) void k_table(const float* __restrict__ table,
                                               float* __restrict__ ws,
                                               float* __restrict__ out) {
    __shared__ float acol[4 * COLSN];
    __shared__ float aop[4 * 16];
    __shared__ float rs3[256];
    __shared__ float wred[4][8];
    int tid = threadIdx.x;
    acol[tid] = ws[WS_ACOL + tid];          // 256 = 4*64
    if (tid < 64) aop[tid] = ws[WS_AOP + tid];
    __syncthreads();
    float gp = ws[WS_PIV + 0];
    float lp = ws[WS_PIV + 1];
    long r = (long)blockIdx.x * 256 + tid;
    bool valid = r < ROWSN;
    float cv[4] = {0,0,0,0}, gs[4] = {0,0,0,0}, ls[4] = {0,0,0,0};
    if (valid) {
        const float4* row4 = (const float4*)(table + r * COLSN);
        #pragma unroll
        for (int c4 = 0; c4 < 16; ++c4) {
            float4 v = row4[c4];
            float xs[4] = {v.x, v.y, v.z, v.w};
            #pragma unroll
            for (int e = 0; e < 4; ++e) {
                int c = c4 * 4 + e;
                float x = xs[e];
                float gt = (x > gp) ? 1.f : 0.f;
                float lt = (x < lp) ? 1.f : 0.f;
                #pragma unroll
                for (int t = 0; t < 4; ++t) {
                    float a = acol[t * COLSN + c];
                    cv[t] += x * a;
                    gs[t] += gt * a;
                    ls[t] += lt * a;
                }
            }
        }
    }
    float prev1 = 1.f, prev2 = 1.f;
    float dotp[4], cntp[4];
    #pragma unroll
    for (int t = 0; t < 4; ++t) {
        dotp[t] = valid ? prev1 * cv[t] : 0.f;
        cntp[t] = valid ? prev1 : 0.f;
        float cg = aop[t*16+3], cl = aop[t*16+4], cmn = aop[t*16+5];
        float cmx = aop[t*16+6], co = aop[t*16+8];
        float cid = aop[t*16+0] + aop[t*16+1] + aop[t*16+2] + aop[t*16+7];
        float rsn = cg * gs[t] + cl * ls[t] + cmn * fminf(prev1, prev2)
                  + cmx * fmaxf(prev1, prev2) + co + cid * prev1;
        prev2 = prev1; prev1 = rsn;
    }
    rs3[tid] = valid ? prev1 * aop[3*16+7] : 0.f;
    __syncthreads();
    // coalesced lookup write (offset by 1 for the scalar output slot)
    long base = (long)blockIdx.x * 256 * COLSN;
    long lim = (long)ROWSN * COLSN;
    for (int idx = tid; idx < 256 * COLSN; idx += 256) {
        long o = base + idx;
        if (o < lim) out[1 + o] = rs3[idx >> 6] * acol[3 * COLSN + (idx & 63)];
    }
    // block-reduce dot[t], cnt[t] then one atomicAdd per block
    #pragma unroll
    for (int t = 0; t < 4; ++t) {
        float d = dotp[t], cn = cntp[t];
        for (int off = 1; off < 64; off <<= 1) { d += __shfl_xor(d, off); cn += __shfl_xor(cn, off); }
        if ((tid & 63) == 0) { int wid = tid >> 6; wred[wid][t] = d; wred[wid][4 + t] = cn; }
    }
    __syncthreads();
    if (tid < 8) {
        float s = wred[0][tid] + wred[1][tid] + wred[2][tid] + wred[3][tid];
        atomicAdd(&ws[WS_ACC + tid], s);
    }
}

// ---- scalar chain ----
__global__ void k_scalar(const float* __restrict__ ws, float* __restrict__ out) {
    float d0 = ws[WS_ACC+0], d1 = ws[WS_ACC+1], d2 = ws[WS_ACC+2], d3 = ws[WS_ACC+3];
    float c0 = ws[WS_ACC+4], c1 = ws[WS_ACC+5], c2 = ws[WS_ACC+6], c3 = ws[WS_ACC+7];
    const float* a0 = &ws[WS_AOP + 0];
    const float* a1 = &ws[WS_AOP + 16];
    const float* a2 = &ws[WS_AOP + 32];
    const float* a3 = &ws[WS_AOP + 48];
    float s0 = a0[0]*d0 + a0[1]*c0;                      // s1=s3=0 at t=0
    float s1 = a1[0]*d1 + a1[1]*c1 + a1[2]*(0.f - s0);
    float s2 = a2[0]*d2 + a2[1]*c2 + a2[2]*(0.f - s1);
    float s3 = a3[0]*d3 + a3[1]*c3 + a3[2]*(s0 - s2);
    out[0] = s3;
}

extern "C" void kernel_launch(void* const* d_in, const int* in_sizes, int n_in,
                              void* d_out, int out_size, void* d_ws, size_t ws_size,
                              hipStream_t stream) {
    const int*   iq      = (const int*)  d_in[0];
    const float* qn      = (const float*)d_in[1];
    const int*   lwi     = (const int*)  d_in[2];
    const float* table   = (const float*)d_in[3];
    const float* E       = (const float*)d_in[4];
    const float* Wx      = (const float*)d_in[5];
    const float* Wh      = (const float*)d_in[6];
    const float* b       = (const float*)d_in[7];
    const float* W_op    = (const float*)d_in[8];
    const float* op_emb  = (const float*)d_in[9];
    const float* W_col   = (const float*)d_in[10];
    const float* col_emb = (const float*)d_in[11];
    const float* U       = (const float*)d_in[12];
    const float* W_hc    = (const float*)d_in[13];
    const float* W_hh    = (const float*)d_in[14];
    float* out = (float*)d_out;
    float* ws  = (float*)d_ws;

    hipLaunchKernelGGL(k_xw,  dim3(QLEN), dim3(H),   0, stream, iq, E, Wx, b, ws);
    hipLaunchKernelGGL(k_rnn, dim3(1),    dim3(512), 0, stream, Wh, lwi, U, qn, ws);
    hipLaunchKernelGGL(k_pq,  dim3(2),    dim3(H),   0, stream, W_op, W_col, ws);
    for (int t = 0; t < T_STEPS; ++t) {
        float* hsrc = ws + ((t & 1) ? WS_HHB : WS_HHA);
        float* hdst = ws + ((t & 1) ? WS_HHA : WS_HHB);
        hipLaunchKernelGGL(k_u,    dim3(16), dim3(256), 0, stream, W_op, W_col, hsrc, ws);
        hipLaunchKernelGGL(k_soft, dim3(1),  dim3(256), 0, stream, t, op_emb, col_emb, ws);
        hipLaunchKernelGGL(k_h,    dim3(8),  dim3(256), 0, stream, W_hc, W_hh, hsrc, hdst, ws);
    }
    hipLaunchKernelGGL(k_table,  dim3((ROWSN + 255) / 256), dim3(256), 0, stream, table, ws, out);
    hipLaunchKernelGGL(k_scalar, dim3(1), dim3(1), 0, stream, ws, out);
}